// Round 1
// baseline (118.237 us; speedup 1.0000x reference)
//
#include <hip/hip_runtime.h>
#include <math.h>

// SUB_Independent_Loss — contrastive pairwise loss, single f32 scalar out.
// N1 = N2 = 256, D = 1024.
//
// Fused structure (2 kernels, was 4):
//   K1 gemm_prep: blocks 0..191 = three NT GEMMs via bf16 MFMA with in-register
//                 f32->bf16 RNE conversion on load (no bf16 staging buffers).
//                 Block 192 = mask_sents decode + accumulator/counter zeroing.
//   K2 loss_finalize: loss over (256 rows x 4 calls); every block increments a
//                 device-scope completion counter; the last block finalizes out.
//
// ws layout:
//   [0)       sims: 3 * 256*256 f32 (sim12, sim11, sim22) = 786432 B
//   [786432)  sel1: 256 f32
//   [787456)  sel2: 256 f32
//   [788480)  lossAcc: double
//   [788488)  pairAcc: unsigned long long
//   [788496)  doneCnt: unsigned int

#define NN 256
#define DD 1024

typedef __attribute__((ext_vector_type(8))) short short8;   // 8 bf16 = 4 VGPRs
typedef __attribute__((ext_vector_type(4))) float f32x4;

__device__ __forceinline__ unsigned short f32_to_bf16_rne(float x) {
    unsigned int u = __float_as_uint(x);
    u += 0x7fffu + ((u >> 16) & 1u);     // round to nearest even (inputs are finite)
    return (unsigned short)(u >> 16);
}

// ---------------------------------------------------------------------------
// Kernel 1: blocks 0..191: one wave per 16x16 output tile, full K=1024
// (32 mfma). 768 tiles -> 192 blocks x 4 waves. Operands loaded as f32
// directly from global (L2-resident) and converted to bf16 in-register with
// the same RNE trick the old convert kernel used -> bit-identical sims.
// A-operand layout: lane holds A[m=lane&15][k = (lane>>4)*8 + j], j=0..7.
// B-operand (NT): same addressing on the B matrix rows (= output cols).
// C/D layout: col = lane&15, row = (lane>>4)*4 + reg.
// Block 192: decodes mask_sents (bool-bytes or int32 auto-detect) and zeroes
// the accumulators + completion counter.
// ---------------------------------------------------------------------------
__global__ __launch_bounds__(256) void gemm_prep_kernel(
        const float* __restrict__ f1, const float* __restrict__ f2,
        const void* ms1, const void* ms2,
        float* __restrict__ sims,
        float* sel1, float* sel2,
        double* lossAcc, unsigned long long* pairAcc, unsigned int* doneCnt) {
    const int bid = blockIdx.x;
    const int tid = threadIdx.x;

    if (bid == 192) {
        // --- prep: mask_sents decode (bool-bytes vs int32), zero accums ---
        // Detection: int32 0/1 data has all-zero bytes at i%4!=0 in the first
        // 256 B; random bool data has ~96 nonzero ones there.
        __shared__ int nz1, nz2;
        if (tid == 0) { nz1 = 0; nz2 = 0; }
        __syncthreads();
        const unsigned char* c1 = (const unsigned char*)ms1;
        const unsigned char* c2 = (const unsigned char*)ms2;
        if ((tid & 3) != 0) {
            if (c1[tid] != 0) atomicOr(&nz1, 1);
            if (c2[tid] != 0) atomicOr(&nz2, 1);
        }
        __syncthreads();
        sel1[tid] = (nz1 != 0) ? (c1[tid] ? 1.0f : 0.0f)
                               : (float)((const int*)ms1)[tid];
        sel2[tid] = (nz2 != 0) ? (c2[tid] ? 1.0f : 0.0f)
                               : (float)((const int*)ms2)[tid];
        if (tid == 0) { *lossAcc = 0.0; *pairAcc = 0ULL; *doneCnt = 0u; }
        return;
    }

    const int gwave = bid * 4 + (tid >> 6);                 // 0..767
    const int m = gwave >> 8;                               // matrix 0..2
    const int t = gwave & 255;                              // tile 0..255
    const int tr = t >> 4, tc = t & 15;
    const float* A  = (m == 2) ? f2 : f1;
    const float* Bm = (m == 0) ? f2 : ((m == 1) ? f1 : f2);
    float* C = sims + m * (NN * NN);

    const int lane = tid & 63;
    const int r = lane & 15;
    const int quad = lane >> 4;

    const float* aptr = A  + (tr * 16 + r) * DD + quad * 8;
    const float* bptr = Bm + (tc * 16 + r) * DD + quad * 8;

    f32x4 acc = {0.f, 0.f, 0.f, 0.f};
#pragma unroll 4
    for (int k0 = 0; k0 < DD; k0 += 32) {
        float4 a0 = *(const float4*)(aptr + k0);
        float4 a1 = *(const float4*)(aptr + k0 + 4);
        float4 b0 = *(const float4*)(bptr + k0);
        float4 b1 = *(const float4*)(bptr + k0 + 4);
        short8 af, bf;
        af[0] = (short)f32_to_bf16_rne(a0.x);
        af[1] = (short)f32_to_bf16_rne(a0.y);
        af[2] = (short)f32_to_bf16_rne(a0.z);
        af[3] = (short)f32_to_bf16_rne(a0.w);
        af[4] = (short)f32_to_bf16_rne(a1.x);
        af[5] = (short)f32_to_bf16_rne(a1.y);
        af[6] = (short)f32_to_bf16_rne(a1.z);
        af[7] = (short)f32_to_bf16_rne(a1.w);
        bf[0] = (short)f32_to_bf16_rne(b0.x);
        bf[1] = (short)f32_to_bf16_rne(b0.y);
        bf[2] = (short)f32_to_bf16_rne(b0.z);
        bf[3] = (short)f32_to_bf16_rne(b0.w);
        bf[4] = (short)f32_to_bf16_rne(b1.x);
        bf[5] = (short)f32_to_bf16_rne(b1.y);
        bf[6] = (short)f32_to_bf16_rne(b1.z);
        bf[7] = (short)f32_to_bf16_rne(b1.w);
        acc = __builtin_amdgcn_mfma_f32_16x16x32_bf16(af, bf, acc, 0, 0, 0);
    }
    const int row0 = tr * 16 + quad * 4;
    const int col = tc * 16 + (lane & 15);
#pragma unroll
    for (int rr = 0; rr < 4; rr++) {
        C[(row0 + rr) * NN + col] = acc[rr];
    }
}

// ---------------------------------------------------------------------------
// Kernel 2: loss + finalize. grid (256 rows, 4 calls), 256 threads/block.
// call 0: sim12 row i / mc row i / sel1;  call 1: sim12 col i / mc col i / sel2
// call 2: sim11 row i / m1 row i / sel1;  call 3: sim22 row i / m2 row i / sel2
// Ballot-compact pos/neg values (pre-scaled by log2e) into LDS; each thread
// holds one neg in a register (pad -1e30 => exact 0 contribution), loops over
// pos with LDS broadcast reads. softplus(x)/ln2 = max(x2,0)+log2(1+2^-|x2|).
// EVERY block (active or not) increments doneCnt; the 1024th block reads the
// accumulators with device-scope atomic RMWs and writes the scalar output.
// ---------------------------------------------------------------------------
__global__ __launch_bounds__(256) void loss_finalize_kernel(
        const float* __restrict__ sims,
        const int* __restrict__ mc,
        const int* __restrict__ m1,
        const int* __restrict__ m2,
        const float* __restrict__ sel1,
        const float* __restrict__ sel2,
        double* lossAcc, unsigned long long* pairAcc,
        unsigned int* doneCnt, float* out) {
    const int i = blockIdx.x;
    const int c = blockIdx.y;
    const int tid = threadIdx.x;

    const float* sim12 = sims;
    const float* sim11 = sims + NN * NN;
    const float* sim22 = sims + 2 * NN * NN;

    float sel;
    if (c == 0)      sel = sel1[i];
    else if (c == 1) sel = sel2[i];
    else if (c == 2) sel = sel1[i];
    else             sel = sel2[i];

    if (sel != 0.0f) {   // block-uniform
        float simv;
        int maskv;
        if (c == 0) {
            simv = sim12[i * NN + tid]; maskv = mc[i * NN + tid];
        } else if (c == 1) {
            simv = sim12[tid * NN + i]; maskv = mc[tid * NN + i];
        } else if (c == 2) {
            simv = sim11[i * NN + tid]; maskv = m1[i * NN + tid];
        } else {
            simv = sim22[i * NN + tid]; maskv = m2[i * NN + tid];
        }

        const float LOG2E = 1.4426950408889634f;
        const float LN2   = 0.6931471805599453f;

        __shared__ float sPos[NN];
        __shared__ float sNeg[NN];
        __shared__ int wcnt[4];
        __shared__ float red[4];

        const int lane = tid & 63;
        const int w = tid >> 6;
        const bool pos = (maskv != 0);
        unsigned long long bal = __ballot(pos);
        if (lane == 0) wcnt[w] = __popcll(bal);
        __syncthreads();

        int posBase = 0, np_ = 0;
#pragma unroll
        for (int q = 0; q < 4; q++) {
            int v = wcnt[q];
            if (q < w) posBase += v;
            np_ += v;
        }
        const int nn_ = NN - np_;

        const unsigned long long ltmask = (1ull << lane) - 1ull;
        const int pp = __popcll(bal & ltmask);
        const float tval = simv * LOG2E;
        if (pos) sPos[posBase + pp] = tval;
        else     sNeg[(w * 64 - posBase) + (lane - pp)] = tval;
        __syncthreads();

        if (np_ != 0 && nn_ != 0) {   // block-uniform
            if (tid == 0) atomicAdd(pairAcc, (unsigned long long)(np_ * nn_));

            const float tn = (tid < nn_) ? sNeg[tid] : -1e30f;  // pad => 0 contrib
            float accL = 0.f, accM = 0.f;
            for (int jj = 0; jj < np_; jj++) {
                float sp = sPos[jj];                  // broadcast, conflict-free
                float x2 = tn - sp;                   // (s_neg - s_pos) * log2e
                float e = __builtin_amdgcn_exp2f(-fabsf(x2));
                accL += __builtin_amdgcn_logf(1.0f + e);   // log2(1+e)
                accM += fmaxf(x2, 0.0f);
            }
            float local = (accL + accM) * LN2;

            // block reduction (4 waves of 64)
#pragma unroll
            for (int off = 32; off > 0; off >>= 1)
                local += __shfl_down(local, off, 64);
            if (lane == 0) red[w] = local;
            __syncthreads();
            if (tid == 0) {
                double bsum = (double)red[0] + (double)red[1] +
                              (double)red[2] + (double)red[3];
                atomicAdd(lossAcc, bsum);
            }
        }
    }

    // --- completion counting + finalize (every block, exactly once) ---
    if (tid == 0) {
        __threadfence();                               // release our atomics
        unsigned int old = atomicAdd(doneCnt, 1u);
        if (old == 1023u) {
            // device-scope atomic RMWs => coherent reads of all blocks' adds
            double loss = atomicAdd(lossAcc, 0.0);
            unsigned long long p = atomicAdd(pairAcc, 0ULL);
            double r = (p > 0ULL) ? (loss / (double)p) : loss;
            out[0] = (float)r;
        }
    }
}

extern "C" void kernel_launch(void* const* d_in, const int* in_sizes, int n_in,
                              void* d_out, int out_size, void* d_ws, size_t ws_size,
                              hipStream_t stream) {
    const float* f1 = (const float*)d_in[0];
    const float* f2 = (const float*)d_in[1];
    const int* mc = (const int*)d_in[2];
    const int* m1 = (const int*)d_in[3];
    const int* m2 = (const int*)d_in[4];
    const void* ms1 = d_in[5];
    const void* ms2 = d_in[6];

    char* ws = (char*)d_ws;
    float* sims          = (float*)ws;                       // 786432 B
    float* sel1          = (float*)(ws + 786432);
    float* sel2          = (float*)(ws + 787456);
    double* lossAcc      = (double*)(ws + 788480);
    unsigned long long* pairAcc = (unsigned long long*)(ws + 788488);
    unsigned int* doneCnt = (unsigned int*)(ws + 788496);

    gemm_prep_kernel<<<193, 256, 0, stream>>>(f1, f2, ms1, ms2, sims,
                                              sel1, sel2, lossAcc, pairAcc,
                                              doneCnt);
    loss_finalize_kernel<<<dim3(256, 4), 256, 0, stream>>>(
        sims, mc, m1, m2, sel1, sel2, lossAcc, pairAcc, doneCnt,
        (float*)d_out);
}

// Round 2
// 101.302 us; speedup vs baseline: 1.1672x; 1.1672x over previous
//
#include <hip/hip_runtime.h>
#include <math.h>

// SUB_Independent_Loss — contrastive pairwise loss, single f32 scalar out.
// N1 = N2 = 256, D = 1024.
//
// Structure (3 kernels):
//   K1 convert_prep: f32->bf16 RNE conversion of f1/f2 (coalesced, once per
//      element) + mask_sents decode + accumulator/counter zeroing.
//   K2 gemm_mfma: three NT GEMMs via bf16 MFMA, one wave per 16x16 tile,
//      768 single-wave blocks (covers all 256 CUs).
//   K3 loss_finalize: loss over (256 rows x 4 calls); every block increments
//      a completion counter with response-ordered atomics (no threadfence);
//      the 1024th block finalizes the scalar output.
//
// ws layout:
//   [0)         sims: 3 * 256*256 f32 (sim12, sim11, sim22)  = 786432 B
//   [786432)    b1: 256*1024 bf16 (f1)                       = 524288 B
//   [1310720)   b2: 256*1024 bf16 (f2)                       = 524288 B
//   [1835008)   sel1: 256 f32
//   [1836032)   sel2: 256 f32
//   [1837056)   lossAcc: double
//   [1837064)   pairAcc: unsigned long long
//   [1837072)   doneCnt: unsigned int

#define NN 256
#define DD 1024

typedef __attribute__((ext_vector_type(8))) short short8;   // 8 bf16 = 4 VGPRs
typedef __attribute__((ext_vector_type(4))) float f32x4;

__device__ __forceinline__ unsigned short f32_to_bf16_rne(float x) {
    unsigned int u = __float_as_uint(x);
    u += 0x7fffu + ((u >> 16) & 1u);     // round to nearest even (inputs are finite)
    return (unsigned short)(u >> 16);
}

// ---------------------------------------------------------------------------
// Kernel 1: blocks 0..511 convert f1/f2 f32 -> bf16 (RNE). Block 512 decodes
// mask_sents (bool-bytes or int32 auto-detect) and zeroes the accumulators.
// Detection: int32 0/1 data has all-zero bytes at i%4!=0 in the first 256 B;
// random bool data has ~96 nonzero ones there (misdetect prob ~2^-192).
// ---------------------------------------------------------------------------
__global__ __launch_bounds__(256) void convert_prep_kernel(
        const float* __restrict__ f1, const float* __restrict__ f2,
        unsigned short* __restrict__ b1, unsigned short* __restrict__ b2,
        const void* ms1, const void* ms2,
        float* sel1, float* sel2,
        double* lossAcc, unsigned long long* pairAcc, unsigned int* doneCnt) {
    const int bid = blockIdx.x;
    const int tid = threadIdx.x;
    if (bid < 512) {
        const float* src = (bid < 256) ? f1 : f2;
        unsigned short* dst = (bid < 256) ? b1 : b2;
        int base = ((bid & 255) * 256 + tid) * 4;       // 4 floats per thread
        float4 v = *(const float4*)(src + base);
        ushort4 o;
        o.x = f32_to_bf16_rne(v.x);
        o.y = f32_to_bf16_rne(v.y);
        o.z = f32_to_bf16_rne(v.z);
        o.w = f32_to_bf16_rne(v.w);
        *(ushort4*)(dst + base) = o;
    } else {
        __shared__ int nz1, nz2;
        if (tid == 0) { nz1 = 0; nz2 = 0; }
        __syncthreads();
        const unsigned char* c1 = (const unsigned char*)ms1;
        const unsigned char* c2 = (const unsigned char*)ms2;
        if ((tid & 3) != 0) {
            if (c1[tid] != 0) atomicOr(&nz1, 1);
            if (c2[tid] != 0) atomicOr(&nz2, 1);
        }
        __syncthreads();
        sel1[tid] = (nz1 != 0) ? (c1[tid] ? 1.0f : 0.0f)
                               : (float)((const int*)ms1)[tid];
        sel2[tid] = (nz2 != 0) ? (c2[tid] ? 1.0f : 0.0f)
                               : (float)((const int*)ms2)[tid];
        if (tid == 0) { *lossAcc = 0.0; *pairAcc = 0ULL; *doneCnt = 0u; }
    }
}

// ---------------------------------------------------------------------------
// Kernel 2: three NT GEMMs via bf16 MFMA. One wave per 16x16 output tile,
// full K=1024 (32 mfma). 768 tiles -> 768 blocks x 1 wave (64 threads),
// spreading waves over all 256 CUs (192x256 left 64 CUs idle). Fragments
// loaded directly from global (L2-resident); per wave-iteration the 64 lanes
// cover 16 rows x 64 contiguous bytes -> 16 cacheline transactions.
// A-operand layout: lane holds A[m=lane&15][k = (lane>>4)*8 + j], j=0..7.
// B-operand (NT): same addressing on the B matrix rows (= output cols).
// C/D layout: col = lane&15, row = (lane>>4)*4 + reg.
// ---------------------------------------------------------------------------
__global__ __launch_bounds__(64) void gemm_mfma(
        const unsigned short* __restrict__ b1,
        const unsigned short* __restrict__ b2,
        float* __restrict__ sims) {
    const int gwave = blockIdx.x;                           // 0..767
    const int m = gwave >> 8;                               // matrix 0..2
    const int t = gwave & 255;                              // tile 0..255
    const int tr = t >> 4, tc = t & 15;
    const unsigned short* A  = (m == 2) ? b2 : b1;
    const unsigned short* Bm = (m == 0) ? b2 : ((m == 1) ? b1 : b2);
    float* C = sims + m * (NN * NN);

    const int lane = threadIdx.x & 63;
    const int r = lane & 15;
    const int quad = lane >> 4;

    const unsigned short* aptr = A  + (tr * 16 + r) * DD + quad * 8;
    const unsigned short* bptr = Bm + (tc * 16 + r) * DD + quad * 8;

    f32x4 acc = {0.f, 0.f, 0.f, 0.f};
#pragma unroll 8
    for (int k0 = 0; k0 < DD; k0 += 32) {
        short8 af = *(const short8*)(aptr + k0);
        short8 bf = *(const short8*)(bptr + k0);
        acc = __builtin_amdgcn_mfma_f32_16x16x32_bf16(af, bf, acc, 0, 0, 0);
    }
    const int row0 = tr * 16 + quad * 4;
    const int col = tc * 16 + (lane & 15);
#pragma unroll
    for (int rr = 0; rr < 4; rr++) {
        C[(row0 + rr) * NN + col] = acc[rr];
    }
}

// ---------------------------------------------------------------------------
// Kernel 3: loss + finalize. grid (256 rows, 4 calls), 256 threads/block.
// call 0: sim12 row i / mc row i / sel1;  call 1: sim12 col i / mc col i / sel2
// call 2: sim11 row i / m1 row i / sel1;  call 3: sim22 row i / m2 row i / sel2
// Ballot-compact pos/neg values (pre-scaled by log2e) into LDS; each thread
// holds one neg in a register (pad -1e30 => exact 0 contribution), loops over
// pos with LDS broadcast reads. softplus(x)/ln2 = max(x2,0)+log2(1+2^-|x2|).
// Completion: EVERY block increments doneCnt exactly once. Active blocks
// first land their pairAcc/lossAcc atomic RMWs and consume the RETURNED
// values (asm sink) -> s_waitcnt for the RMW response precedes the doneCnt
// RMW in issue order, so the accumulator updates are globally visible (all
// accumulator accesses are device-scope RMWs at the coherent point) before
// the completion signal. No threadfence / L2 writeback needed.
// ---------------------------------------------------------------------------
__global__ __launch_bounds__(256) void loss_finalize_kernel(
        const float* __restrict__ sims,
        const int* __restrict__ mc,
        const int* __restrict__ m1,
        const int* __restrict__ m2,
        const float* __restrict__ sel1,
        const float* __restrict__ sel2,
        double* lossAcc, unsigned long long* pairAcc,
        unsigned int* doneCnt, float* out) {
    const int i = blockIdx.x;
    const int c = blockIdx.y;
    const int tid = threadIdx.x;

    const float* sim12 = sims;
    const float* sim11 = sims + NN * NN;
    const float* sim22 = sims + 2 * NN * NN;

    const float sel = (c == 0 || c == 2) ? sel1[i] : sel2[i];

    int np_ = 0, nn_ = 0;
    double bsum = 0.0;

    if (sel != 0.0f) {   // block-uniform
        float simv;
        int maskv;
        if (c == 0) {
            simv = sim12[i * NN + tid]; maskv = mc[i * NN + tid];
        } else if (c == 1) {
            simv = sim12[tid * NN + i]; maskv = mc[tid * NN + i];
        } else if (c == 2) {
            simv = sim11[i * NN + tid]; maskv = m1[i * NN + tid];
        } else {
            simv = sim22[i * NN + tid]; maskv = m2[i * NN + tid];
        }

        const float LOG2E = 1.4426950408889634f;
        const float LN2   = 0.6931471805599453f;

        __shared__ float sPos[NN];
        __shared__ float sNeg[NN];
        __shared__ int wcnt[4];
        __shared__ float red[4];

        const int lane = tid & 63;
        const int w = tid >> 6;
        const bool pos = (maskv != 0);
        unsigned long long bal = __ballot(pos);
        if (lane == 0) wcnt[w] = __popcll(bal);
        __syncthreads();

        int posBase = 0;
#pragma unroll
        for (int q = 0; q < 4; q++) {
            int v = wcnt[q];
            if (q < w) posBase += v;
            np_ += v;
        }
        nn_ = NN - np_;

        const unsigned long long ltmask = (1ull << lane) - 1ull;
        const int pp = __popcll(bal & ltmask);
        const float tval = simv * LOG2E;
        if (pos) sPos[posBase + pp] = tval;
        else     sNeg[(w * 64 - posBase) + (lane - pp)] = tval;
        __syncthreads();

        if (np_ != 0 && nn_ != 0) {   // block-uniform
            const float tn = (tid < nn_) ? sNeg[tid] : -1e30f;  // pad => 0 contrib
            float accL = 0.f, accM = 0.f;
            for (int jj = 0; jj < np_; jj++) {
                float sp = sPos[jj];                  // broadcast, conflict-free
                float x2 = tn - sp;                   // (s_neg - s_pos) * log2e
                float e = __builtin_amdgcn_exp2f(-fabsf(x2));
                accL += __builtin_amdgcn_logf(1.0f + e);   // log2(1+e)
                accM += fmaxf(x2, 0.0f);
            }
            float local = (accL + accM) * LN2;

            // block reduction (4 waves of 64)
#pragma unroll
            for (int off = 32; off > 0; off >>= 1)
                local += __shfl_down(local, off, 64);
            if (lane == 0) red[w] = local;
            __syncthreads();
            if (tid == 0) {
                bsum = (double)red[0] + (double)red[1] +
                       (double)red[2] + (double)red[3];
            }
        }
    }

    // --- completion counting + finalize (tid 0 of every block, exactly once)
    if (tid == 0) {
        if (np_ != 0 && nn_ != 0) {
            unsigned long long pprev =
                atomicAdd(pairAcc, (unsigned long long)(np_ * nn_));
            double lprev = atomicAdd(lossAcc, bsum);
            // Consume the RMW responses: forces s_waitcnt vmcnt before the
            // doneCnt atomic issues -> our adds are at the coherent point
            // before the completion signal can be observed.
            __asm__ volatile("" :: "v"(pprev), "v"(lprev));
        }
        unsigned int old = atomicAdd(doneCnt, 1u);
        if (old == 1023u) {
            // Device-scope RMW reads -> coherent view of all blocks' adds.
            double loss = atomicAdd(lossAcc, 0.0);
            unsigned long long p = atomicAdd(pairAcc, 0ULL);
            double r = (p > 0ULL) ? (loss / (double)p) : loss;
            out[0] = (float)r;
        }
    }
}

extern "C" void kernel_launch(void* const* d_in, const int* in_sizes, int n_in,
                              void* d_out, int out_size, void* d_ws, size_t ws_size,
                              hipStream_t stream) {
    const float* f1 = (const float*)d_in[0];
    const float* f2 = (const float*)d_in[1];
    const int* mc = (const int*)d_in[2];
    const int* m1 = (const int*)d_in[3];
    const int* m2 = (const int*)d_in[4];
    const void* ms1 = d_in[5];
    const void* ms2 = d_in[6];

    char* ws = (char*)d_ws;
    float* sims          = (float*)ws;                       // 786432 B
    unsigned short* b1   = (unsigned short*)(ws + 786432);   // 524288 B
    unsigned short* b2   = (unsigned short*)(ws + 1310720);  // 524288 B
    float* sel1          = (float*)(ws + 1835008);
    float* sel2          = (float*)(ws + 1836032);
    double* lossAcc      = (double*)(ws + 1837056);
    unsigned long long* pairAcc = (unsigned long long*)(ws + 1837064);
    unsigned int* doneCnt = (unsigned int*)(ws + 1837072);

    convert_prep_kernel<<<513, 256, 0, stream>>>(f1, f2, b1, b2, ms1, ms2,
                                                 sel1, sel2, lossAcc, pairAcc,
                                                 doneCnt);
    gemm_mfma<<<768, 64, 0, stream>>>(b1, b2, sims);
    loss_finalize_kernel<<<dim3(256, 4), 256, 0, stream>>>(
        sims, mc, m1, m2, sel1, sel2, lossAcc, pairAcc, doneCnt,
        (float*)d_out);
}

// Round 3
// 92.857 us; speedup vs baseline: 1.2733x; 1.0909x over previous
//
#include <hip/hip_runtime.h>
#include <math.h>

// SUB_Independent_Loss — contrastive pairwise loss, single f32 scalar out.
// N1 = N2 = 256, D = 1024.
//
// Structure (4 kernels — round-0 verified structure, GEMM upgraded to 32x32):
//   K1 convert_prep: f32->bf16 RNE conversion of f1/f2 + mask_sents decode +
//      accumulator zeroing.
//   K2 gemm_mfma: three NT GEMMs via bf16 MFMA 32x32x16, one wave per 32x32
//      output tile (halves L2 operand re-reads vs 16x16 tiles: 48 MB -> 24 MB).
//   K3 loss_kernel: loss over (256 rows x 4 calls).
//   K4 finalize_kernel: scalar division. (A fused grid-wide completion counter
//      was tried and cost +11 us: 1024 same-line device atomics serialize at
//      ~10 ns each — worse than a 4th launch. Keep the tiny kernel.)
//
// ws layout:
//   [0)         sims: 3 * 256*256 f32 (sim12, sim11, sim22)  = 786432 B
//   [786432)    b1: 256*1024 bf16 (f1)                       = 524288 B
//   [1310720)   b2: 256*1024 bf16 (f2)                       = 524288 B
//   [1835008)   sel1: 256 f32
//   [1836032)   sel2: 256 f32
//   [1837056)   lossAcc: double
//   [1837064)   pairAcc: unsigned long long

#define NN 256
#define DD 1024

typedef __attribute__((ext_vector_type(8))) short short8;    // 8 bf16 = 4 VGPRs
typedef __attribute__((ext_vector_type(16))) float f32x16;   // 32x32 accumulator

__device__ __forceinline__ unsigned short f32_to_bf16_rne(float x) {
    unsigned int u = __float_as_uint(x);
    u += 0x7fffu + ((u >> 16) & 1u);     // round to nearest even (inputs are finite)
    return (unsigned short)(u >> 16);
}

// ---------------------------------------------------------------------------
// Kernel 1: blocks 0..511 convert f1/f2 f32 -> bf16 (RNE). Block 512 decodes
// mask_sents (bool-bytes or int32 auto-detect) and zeroes the accumulators.
// Detection: int32 0/1 data has all-zero bytes at i%4!=0 in the first 256 B;
// random bool data has ~96 nonzero ones there (misdetect prob ~2^-192).
// ---------------------------------------------------------------------------
__global__ __launch_bounds__(256) void convert_prep_kernel(
        const float* __restrict__ f1, const float* __restrict__ f2,
        unsigned short* __restrict__ b1, unsigned short* __restrict__ b2,
        const void* ms1, const void* ms2,
        float* sel1, float* sel2,
        double* lossAcc, unsigned long long* pairAcc) {
    const int bid = blockIdx.x;
    const int tid = threadIdx.x;
    if (bid < 512) {
        const float* src = (bid < 256) ? f1 : f2;
        unsigned short* dst = (bid < 256) ? b1 : b2;
        int base = ((bid & 255) * 256 + tid) * 4;       // 4 floats per thread
        float4 v = *(const float4*)(src + base);
        ushort4 o;
        o.x = f32_to_bf16_rne(v.x);
        o.y = f32_to_bf16_rne(v.y);
        o.z = f32_to_bf16_rne(v.z);
        o.w = f32_to_bf16_rne(v.w);
        *(ushort4*)(dst + base) = o;
    } else {
        __shared__ int nz1, nz2;
        if (tid == 0) { nz1 = 0; nz2 = 0; }
        __syncthreads();
        const unsigned char* c1 = (const unsigned char*)ms1;
        const unsigned char* c2 = (const unsigned char*)ms2;
        if ((tid & 3) != 0) {
            if (c1[tid] != 0) atomicOr(&nz1, 1);
            if (c2[tid] != 0) atomicOr(&nz2, 1);
        }
        __syncthreads();
        sel1[tid] = (nz1 != 0) ? (c1[tid] ? 1.0f : 0.0f)
                               : (float)((const int*)ms1)[tid];
        sel2[tid] = (nz2 != 0) ? (c2[tid] ? 1.0f : 0.0f)
                               : (float)((const int*)ms2)[tid];
        if (tid == 0) { *lossAcc = 0.0; *pairAcc = 0ULL; }
    }
}

// ---------------------------------------------------------------------------
// Kernel 2: three NT GEMMs via bf16 MFMA 32x32x16. One wave per 32x32 output
// tile, full K=1024 (64 mfma). 3 * 64 = 192 tiles -> 192 blocks x 1 wave,
// spread across CUs. Fragments loaded directly from global (L2-resident);
// per-tile operand bytes: 2 * 32 rows * 2 KB = 128 KB -> 24 MB total L2 reads
// (vs 48 MB with 16x16 tiles).
// A-operand layout: lane holds A[m=lane&31][k = (lane>>5)*8 + j], j=0..7.
// B-operand (NT): same addressing on the B matrix rows (= output cols).
// C/D layout (HW-verified): col = lane&31, row = (reg&3) + 8*(reg>>2) +
// 4*(lane>>5), reg = 0..15.
// ---------------------------------------------------------------------------
__global__ __launch_bounds__(64) void gemm_mfma(
        const unsigned short* __restrict__ b1,
        const unsigned short* __restrict__ b2,
        float* __restrict__ sims) {
    const int gwave = blockIdx.x;                           // 0..191
    const int m = gwave >> 6;                               // matrix 0..2
    const int t = gwave & 63;                               // tile 0..63
    const int tr = t >> 3, tc = t & 7;
    const unsigned short* A  = (m == 2) ? b2 : b1;
    const unsigned short* Bm = (m == 0) ? b2 : ((m == 1) ? b1 : b2);
    float* C = sims + m * (NN * NN);

    const int lane = threadIdx.x & 63;
    const int r = lane & 31;
    const int half = lane >> 5;

    const unsigned short* aptr = A  + (tr * 32 + r) * DD + half * 8;
    const unsigned short* bptr = Bm + (tc * 32 + r) * DD + half * 8;

    f32x16 acc;
#pragma unroll
    for (int z = 0; z < 16; z++) acc[z] = 0.0f;

#pragma unroll 8
    for (int k0 = 0; k0 < DD; k0 += 16) {
        short8 af = *(const short8*)(aptr + k0);
        short8 bf = *(const short8*)(bptr + k0);
        acc = __builtin_amdgcn_mfma_f32_32x32x16_bf16(af, bf, acc, 0, 0, 0);
    }

    const int col = tc * 32 + r;
    const int row0 = tr * 32 + 4 * half;
#pragma unroll
    for (int reg = 0; reg < 16; reg++) {
        int row = row0 + (reg & 3) + 8 * (reg >> 2);
        C[row * NN + col] = acc[reg];
    }
}

// ---------------------------------------------------------------------------
// Kernel 3: loss. grid (256 rows, 4 calls), 256 threads/block.
// call 0: sim12 row i / mc row i / sel1;  call 1: sim12 col i / mc col i / sel2
// call 2: sim11 row i / m1 row i / sel1;  call 3: sim22 row i / m2 row i / sel2
// Ballot-compact pos/neg values (pre-scaled by log2e) into LDS; each thread
// holds one neg in a register (pad -1e30 => exact 0 contribution), loops over
// pos with LDS broadcast reads. softplus(x)/ln2 = max(x2,0)+log2(1+2^-|x2|).
// ---------------------------------------------------------------------------
__global__ __launch_bounds__(256) void loss_kernel(
        const float* __restrict__ sims,
        const int* __restrict__ mc,
        const int* __restrict__ m1,
        const int* __restrict__ m2,
        const float* __restrict__ sel1,
        const float* __restrict__ sel2,
        double* lossAcc, unsigned long long* pairAcc) {
    const int i = blockIdx.x;
    const int c = blockIdx.y;
    const int tid = threadIdx.x;

    const float* sim12 = sims;
    const float* sim11 = sims + NN * NN;
    const float* sim22 = sims + 2 * NN * NN;

    float sel, simv;
    int maskv;
    if (c == 0) {
        sel = sel1[i]; simv = sim12[i * NN + tid]; maskv = mc[i * NN + tid];
    } else if (c == 1) {
        sel = sel2[i]; simv = sim12[tid * NN + i]; maskv = mc[tid * NN + i];
    } else if (c == 2) {
        sel = sel1[i]; simv = sim11[i * NN + tid]; maskv = m1[i * NN + tid];
    } else {
        sel = sel2[i]; simv = sim22[i * NN + tid]; maskv = m2[i * NN + tid];
    }
    if (sel == 0.0f) return;  // block-uniform

    const float LOG2E = 1.4426950408889634f;
    const float LN2   = 0.6931471805599453f;

    __shared__ float sPos[NN];
    __shared__ float sNeg[NN];
    __shared__ int wcnt[4];
    __shared__ float red[4];

    const int lane = tid & 63;
    const int w = tid >> 6;
    const bool pos = (maskv != 0);
    unsigned long long bal = __ballot(pos);
    if (lane == 0) wcnt[w] = __popcll(bal);
    __syncthreads();

    int posBase = 0, np_ = 0;
#pragma unroll
    for (int q = 0; q < 4; q++) {
        int v = wcnt[q];
        if (q < w) posBase += v;
        np_ += v;
    }
    const int nn_ = NN - np_;

    const unsigned long long ltmask = (1ull << lane) - 1ull;
    const int pp = __popcll(bal & ltmask);
    const float tval = simv * LOG2E;
    if (pos) sPos[posBase + pp] = tval;
    else     sNeg[(w * 64 - posBase) + (lane - pp)] = tval;
    __syncthreads();

    if (np_ == 0 || nn_ == 0) return;  // block-uniform
    if (tid == 0) atomicAdd(pairAcc, (unsigned long long)(np_ * nn_));

    const float tn = (tid < nn_) ? sNeg[tid] : -1e30f;  // pad => 0 contribution
    float accL = 0.f, accM = 0.f;
    for (int jj = 0; jj < np_; jj++) {
        float sp = sPos[jj];                  // broadcast, conflict-free
        float x2 = tn - sp;                   // (s_neg - s_pos) * log2e
        float e = __builtin_amdgcn_exp2f(-fabsf(x2));
        accL += __builtin_amdgcn_logf(1.0f + e);   // log2(1+e)
        accM += fmaxf(x2, 0.0f);
    }
    float local = (accL + accM) * LN2;

    // block reduction (4 waves of 64)
#pragma unroll
    for (int off = 32; off > 0; off >>= 1) local += __shfl_down(local, off, 64);
    if (lane == 0) red[w] = local;
    __syncthreads();
    if (tid == 0) {
        double bsum = (double)red[0] + (double)red[1] +
                      (double)red[2] + (double)red[3];
        atomicAdd(lossAcc, bsum);
    }
}

// ---------------------------------------------------------------------------
// Kernel 4: finalize scalar.
// ---------------------------------------------------------------------------
__global__ void finalize_kernel(const double* lossAcc,
                                const unsigned long long* pairAcc,
                                float* out) {
    double loss = *lossAcc;
    unsigned long long p = *pairAcc;
    double r = (p > 0ULL) ? (loss / (double)p) : loss;
    out[0] = (float)r;
}

extern "C" void kernel_launch(void* const* d_in, const int* in_sizes, int n_in,
                              void* d_out, int out_size, void* d_ws, size_t ws_size,
                              hipStream_t stream) {
    const float* f1 = (const float*)d_in[0];
    const float* f2 = (const float*)d_in[1];
    const int* mc = (const int*)d_in[2];
    const int* m1 = (const int*)d_in[3];
    const int* m2 = (const int*)d_in[4];
    const void* ms1 = d_in[5];
    const void* ms2 = d_in[6];

    char* ws = (char*)d_ws;
    float* sims          = (float*)ws;                       // 786432 B
    unsigned short* b1   = (unsigned short*)(ws + 786432);   // 524288 B
    unsigned short* b2   = (unsigned short*)(ws + 1310720);  // 524288 B
    float* sel1          = (float*)(ws + 1835008);
    float* sel2          = (float*)(ws + 1836032);
    double* lossAcc      = (double*)(ws + 1837056);
    unsigned long long* pairAcc = (unsigned long long*)(ws + 1837064);

    convert_prep_kernel<<<513, 256, 0, stream>>>(f1, f2, b1, b2, ms1, ms2,
                                                 sel1, sel2, lossAcc, pairAcc);
    gemm_mfma<<<192, 64, 0, stream>>>(b1, b2, sims);
    loss_kernel<<<dim3(256, 4), 256, 0, stream>>>(sims, mc, m1, m2, sel1, sel2,
                                                  lossAcc, pairAcc);
    finalize_kernel<<<1, 1, 0, stream>>>(lossAcc, pairAcc, (float*)d_out);
}

// Round 4
// 91.401 us; speedup vs baseline: 1.2936x; 1.0159x over previous
//
#include <hip/hip_runtime.h>
#include <math.h>

// SUB_Independent_Loss — contrastive pairwise loss, single f32 scalar out.
// N1 = N2 = 256, D = 1024.
//
// ROUND-0 VERIFIED STRUCTURE (measured 90.3 us; best of 5 variants).
// Experiment ledger from this session:
//   R1 FAILED (+28 us): fused f32-direct GEMM (re-converts operands 48x,
//      doubles uncoalesced L2 requests, 1 wave/SIMD) + __threadfence epilogue.
//   R2 FAILED (+11 us): 1024-block single-address doneCnt completion counter
//      serializes device-scope atomics at the coherent point (~10 ns each) —
//      costs more than the finalize launch it replaced.
//   R3 FAILED (+2.6 us): 32x32x16 MFMA tiles halve L2 traffic but cut wave
//      count 4x (768 -> 192 single-wave blocks) — GEMM was latency-hidden,
//      not L2-BW-bound; lost TLP > saved bandwidth.
// Timed region decomposition: ~81 us harness re-poison fills (2 x 262 MB at
// ~6.6 TB/s = achievable HBM ceiling, uncontrollable) + ~9 us kernels/gaps.
//
// ws layout:
//   [0)         sims: 3 * 256*256 f32 (sim12, sim11, sim22)  = 786432 B
//   [786432)    b1: 256*1024 bf16 (f1)                       = 524288 B
//   [1310720)   b2: 256*1024 bf16 (f2)                       = 524288 B
//   [1835008)   sel1: 256 f32
//   [1836032)   sel2: 256 f32
//   [1837056)   lossAcc: double
//   [1837064)   pairAcc: unsigned long long

#define NN 256
#define DD 1024

typedef __attribute__((ext_vector_type(8))) short short8;   // 8 bf16 = 4 VGPRs
typedef __attribute__((ext_vector_type(4))) float f32x4;

__device__ __forceinline__ unsigned short f32_to_bf16_rne(float x) {
    unsigned int u = __float_as_uint(x);
    u += 0x7fffu + ((u >> 16) & 1u);     // round to nearest even (inputs are finite)
    return (unsigned short)(u >> 16);
}

// ---------------------------------------------------------------------------
// Kernel 1: blocks 0..511 convert f1/f2 f32 -> bf16 (RNE). Block 512 decodes
// mask_sents (bool-bytes or int32 auto-detect) and zeroes the accumulators.
// Detection: int32 0/1 data has all-zero bytes at i%4!=0 in the first 256 B;
// random bool data has ~96 nonzero ones there (misdetect prob ~2^-192).
// ---------------------------------------------------------------------------
__global__ __launch_bounds__(256) void convert_prep_kernel(
        const float* __restrict__ f1, const float* __restrict__ f2,
        unsigned short* __restrict__ b1, unsigned short* __restrict__ b2,
        const void* ms1, const void* ms2,
        float* sel1, float* sel2,
        double* lossAcc, unsigned long long* pairAcc) {
    const int bid = blockIdx.x;
    const int tid = threadIdx.x;
    if (bid < 512) {
        const float* src = (bid < 256) ? f1 : f2;
        unsigned short* dst = (bid < 256) ? b1 : b2;
        int base = ((bid & 255) * 256 + tid) * 4;       // 4 floats per thread
        float4 v = *(const float4*)(src + base);
        ushort4 o;
        o.x = f32_to_bf16_rne(v.x);
        o.y = f32_to_bf16_rne(v.y);
        o.z = f32_to_bf16_rne(v.z);
        o.w = f32_to_bf16_rne(v.w);
        *(ushort4*)(dst + base) = o;
    } else {
        __shared__ int nz1, nz2;
        if (tid == 0) { nz1 = 0; nz2 = 0; }
        __syncthreads();
        const unsigned char* c1 = (const unsigned char*)ms1;
        const unsigned char* c2 = (const unsigned char*)ms2;
        if ((tid & 3) != 0) {
            if (c1[tid] != 0) atomicOr(&nz1, 1);
            if (c2[tid] != 0) atomicOr(&nz2, 1);
        }
        __syncthreads();
        sel1[tid] = (nz1 != 0) ? (c1[tid] ? 1.0f : 0.0f)
                               : (float)((const int*)ms1)[tid];
        sel2[tid] = (nz2 != 0) ? (c2[tid] ? 1.0f : 0.0f)
                               : (float)((const int*)ms2)[tid];
        if (tid == 0) { *lossAcc = 0.0; *pairAcc = 0ULL; }
    }
}

// ---------------------------------------------------------------------------
// Kernel 2: three NT GEMMs via bf16 MFMA. One wave per 16x16 output tile,
// full K=1024 (32 mfma). 768 tiles -> 192 blocks x 4 waves (4 waves/CU gives
// the TLP that hides L2 latency — do NOT trade for bigger tiles, see R3).
// Fragments loaded directly from global (L2-resident).
// A-operand layout: lane holds A[m=lane&15][k = (lane>>4)*8 + j], j=0..7.
// B-operand (NT): same addressing on the B matrix rows (= output cols).
// C/D layout: col = lane&15, row = (lane>>4)*4 + reg.
// ---------------------------------------------------------------------------
__global__ __launch_bounds__(256) void gemm_mfma(
        const unsigned short* __restrict__ b1,
        const unsigned short* __restrict__ b2,
        float* __restrict__ sims) {
    const int gwave = blockIdx.x * 4 + (threadIdx.x >> 6);  // 0..767
    const int m = gwave >> 8;                               // matrix 0..2
    const int t = gwave & 255;                              // tile 0..255
    const int tr = t >> 4, tc = t & 15;
    const unsigned short* A  = (m == 2) ? b2 : b1;
    const unsigned short* Bm = (m == 0) ? b2 : ((m == 1) ? b1 : b2);
    float* C = sims + m * (NN * NN);

    const int lane = threadIdx.x & 63;
    const int r = lane & 15;
    const int quad = lane >> 4;

    const unsigned short* aptr = A  + (tr * 16 + r) * DD + quad * 8;
    const unsigned short* bptr = Bm + (tc * 16 + r) * DD + quad * 8;

    f32x4 acc = {0.f, 0.f, 0.f, 0.f};
#pragma unroll 8
    for (int k0 = 0; k0 < DD; k0 += 32) {
        short8 af = *(const short8*)(aptr + k0);
        short8 bf = *(const short8*)(bptr + k0);
        acc = __builtin_amdgcn_mfma_f32_16x16x32_bf16(af, bf, acc, 0, 0, 0);
    }
    const int row0 = tr * 16 + quad * 4;
    const int col = tc * 16 + (lane & 15);
#pragma unroll
    for (int rr = 0; rr < 4; rr++) {
        C[(row0 + rr) * NN + col] = acc[rr];
    }
}

// ---------------------------------------------------------------------------
// Kernel 3: loss. grid (256 rows, 4 calls), 256 threads/block.
// call 0: sim12 row i / mc row i / sel1;  call 1: sim12 col i / mc col i / sel2
// call 2: sim11 row i / m1 row i / sel1;  call 3: sim22 row i / m2 row i / sel2
// Ballot-compact pos/neg values (pre-scaled by log2e) into LDS; each thread
// holds one neg in a register (pad -1e30 => exact 0 contribution), loops over
// pos with LDS broadcast reads. softplus(x)/ln2 = max(x2,0)+log2(1+2^-|x2|).
// ---------------------------------------------------------------------------
__global__ __launch_bounds__(256) void loss_kernel(
        const float* __restrict__ sims,
        const int* __restrict__ mc,
        const int* __restrict__ m1,
        const int* __restrict__ m2,
        const float* __restrict__ sel1,
        const float* __restrict__ sel2,
        double* lossAcc, unsigned long long* pairAcc) {
    const int i = blockIdx.x;
    const int c = blockIdx.y;
    const int tid = threadIdx.x;

    const float* sim12 = sims;
    const float* sim11 = sims + NN * NN;
    const float* sim22 = sims + 2 * NN * NN;

    float sel, simv;
    int maskv;
    if (c == 0) {
        sel = sel1[i]; simv = sim12[i * NN + tid]; maskv = mc[i * NN + tid];
    } else if (c == 1) {
        sel = sel2[i]; simv = sim12[tid * NN + i]; maskv = mc[tid * NN + i];
    } else if (c == 2) {
        sel = sel1[i]; simv = sim11[i * NN + tid]; maskv = m1[i * NN + tid];
    } else {
        sel = sel2[i]; simv = sim22[i * NN + tid]; maskv = m2[i * NN + tid];
    }
    if (sel == 0.0f) return;  // block-uniform

    const float LOG2E = 1.4426950408889634f;
    const float LN2   = 0.6931471805599453f;

    __shared__ float sPos[NN];
    __shared__ float sNeg[NN];
    __shared__ int wcnt[4];
    __shared__ float red[4];

    const int lane = tid & 63;
    const int w = tid >> 6;
    const bool pos = (maskv != 0);
    unsigned long long bal = __ballot(pos);
    if (lane == 0) wcnt[w] = __popcll(bal);
    __syncthreads();

    int posBase = 0, np_ = 0;
#pragma unroll
    for (int q = 0; q < 4; q++) {
        int v = wcnt[q];
        if (q < w) posBase += v;
        np_ += v;
    }
    const int nn_ = NN - np_;

    const unsigned long long ltmask = (1ull << lane) - 1ull;
    const int pp = __popcll(bal & ltmask);
    const float tval = simv * LOG2E;
    if (pos) sPos[posBase + pp] = tval;
    else     sNeg[(w * 64 - posBase) + (lane - pp)] = tval;
    __syncthreads();

    if (np_ == 0 || nn_ == 0) return;  // block-uniform
    if (tid == 0) atomicAdd(pairAcc, (unsigned long long)(np_ * nn_));

    const float tn = (tid < nn_) ? sNeg[tid] : -1e30f;  // pad => 0 contribution
    float accL = 0.f, accM = 0.f;
    for (int jj = 0; jj < np_; jj++) {
        float sp = sPos[jj];                  // broadcast, conflict-free
        float x2 = tn - sp;                   // (s_neg - s_pos) * log2e
        float e = __builtin_amdgcn_exp2f(-fabsf(x2));
        accL += __builtin_amdgcn_logf(1.0f + e);   // log2(1+e)
        accM += fmaxf(x2, 0.0f);
    }
    float local = (accL + accM) * LN2;

    // block reduction (4 waves of 64)
#pragma unroll
    for (int off = 32; off > 0; off >>= 1) local += __shfl_down(local, off, 64);
    if (lane == 0) red[w] = local;
    __syncthreads();
    if (tid == 0) {
        double bsum = (double)red[0] + (double)red[1] +
                      (double)red[2] + (double)red[3];
        atomicAdd(lossAcc, bsum);
    }
}

// ---------------------------------------------------------------------------
// Kernel 4: finalize scalar.
// ---------------------------------------------------------------------------
__global__ void finalize_kernel(const double* lossAcc,
                                const unsigned long long* pairAcc,
                                float* out) {
    double loss = *lossAcc;
    unsigned long long p = *pairAcc;
    double r = (p > 0ULL) ? (loss / (double)p) : loss;
    out[0] = (float)r;
}

extern "C" void kernel_launch(void* const* d_in, const int* in_sizes, int n_in,
                              void* d_out, int out_size, void* d_ws, size_t ws_size,
                              hipStream_t stream) {
    const float* f1 = (const float*)d_in[0];
    const float* f2 = (const float*)d_in[1];
    const int* mc = (const int*)d_in[2];
    const int* m1 = (const int*)d_in[3];
    const int* m2 = (const int*)d_in[4];
    const void* ms1 = d_in[5];
    const void* ms2 = d_in[6];

    char* ws = (char*)d_ws;
    float* sims          = (float*)ws;                       // 786432 B
    unsigned short* b1   = (unsigned short*)(ws + 786432);   // 524288 B
    unsigned short* b2   = (unsigned short*)(ws + 1310720);  // 524288 B
    float* sel1          = (float*)(ws + 1835008);
    float* sel2          = (float*)(ws + 1836032);
    double* lossAcc      = (double*)(ws + 1837056);
    unsigned long long* pairAcc = (unsigned long long*)(ws + 1837064);

    convert_prep_kernel<<<513, 256, 0, stream>>>(f1, f2, b1, b2, ms1, ms2,
                                                 sel1, sel2, lossAcc, pairAcc);
    gemm_mfma<<<192, 256, 0, stream>>>(b1, b2, sims);
    loss_kernel<<<dim3(256, 4), 256, 0, stream>>>(sims, mc, m1, m2, sel1, sel2,
                                                  lossAcc, pairAcc);
    finalize_kernel<<<1, 1, 0, stream>>>(lossAcc, pairAcc, (float*)d_out);
}